// Round 1
// baseline (383.594 us; speedup 1.0000x reference)
//
#include <hip/hip_runtime.h>
#include <stdint.h>

typedef _Float16 f16;
typedef _Float16 f16x8 __attribute__((ext_vector_type(8)));
typedef _Float16 f16x4 __attribute__((ext_vector_type(4)));
typedef float floatx4 __attribute__((ext_vector_type(4)));

#define TT 64
#define CDIM 384
#define HH 64
#define NKK 12          // CDIM / 32 k-steps
#define LDP 72          // padded LDS row stride (2-way bank aliasing = free)
#define SCALE 0.05103103630798288f   // 384^-0.5 (reference scales by C^-0.5)

// Pre-pass: write Wq/Wk/Wv as fp16 in exact MFMA B-fragment order:
// ws layout [kk][p][tile][lane] of f16x8; lane holds W[k=kk*32+quad*8+j][n=tile*16+(lane&15)]
__global__ void prep_w(const float* __restrict__ Wq,
                       const float* __restrict__ Wk,
                       const float* __restrict__ Wv,
                       f16* __restrict__ wf) {
    int t = blockIdx.x * 256 + threadIdx.x;
    if (t >= 3 * NKK * 4 * 64) return;
    int lane = t & 63;
    int tile = (t >> 6) & 3;
    int p    = (t >> 8) % 3;
    int kk   = t / 768;
    const float* W = (p == 0) ? Wq : ((p == 1) ? Wk : Wv);
    int n  = tile * 16 + (lane & 15);
    int k0 = kk * 32 + (lane >> 4) * 8;
    f16x8 frag;
#pragma unroll
    for (int j = 0; j < 8; ++j) frag[j] = (f16)W[(k0 + j) * HH + n];
    ((f16x8*)wf)[t] = frag;
}

__launch_bounds__(256)
__global__ void attn_head(const float* __restrict__ x,
                          const f16* __restrict__ wf,
                          float* __restrict__ out) {
    __shared__ __align__(16) f16 qs [TT * LDP];
    __shared__ __align__(16) f16 ksm[TT * LDP];
    __shared__ __align__(16) f16 vst[TT * LDP];   // v transposed: vst[h][t]
    __shared__ __align__(16) f16 ps [TT * LDP];
    __shared__ __align__(16) f16 wchunk[3 * 4 * 64 * 8];  // 12288 B, fragment-linear

    const int b    = blockIdx.x;
    const int tid  = threadIdx.x;
    const int wave = tid >> 6;
    const int lane = tid & 63;
    const int quad = lane >> 4;
    const int cl   = lane & 15;
    const int row0 = wave * 16;

    const floatx4 fzero = {0.f, 0.f, 0.f, 0.f};

    // ---- load X once from HBM directly into A-fragment registers ----
    // lane holds x[b][row0+cl][kk*32 + quad*8 + j], j=0..7
    const float* xp = x + ((size_t)b * TT + row0 + cl) * CDIM + quad * 8;
    f16x8 xf[NKK];
#pragma unroll
    for (int kk = 0; kk < NKK; ++kk) {
        float4 f0 = *(const float4*)(xp + kk * 32);
        float4 f1 = *(const float4*)(xp + kk * 32 + 4);
        f16x8 f;
        f[0]=(f16)f0.x; f[1]=(f16)f0.y; f[2]=(f16)f0.z; f[3]=(f16)f0.w;
        f[4]=(f16)f1.x; f[5]=(f16)f1.y; f[6]=(f16)f1.z; f[7]=(f16)f1.w;
        xf[kk] = f;
    }

    // ---- q,k,v projections in a single K-loop (3x4 accumulator tiles) ----
    floatx4 acc[3][4];
#pragma unroll
    for (int p = 0; p < 3; ++p)
#pragma unroll
        for (int t = 0; t < 4; ++t) acc[p][t] = fzero;

    const uint4* wg = (const uint4*)wf;
    uint4* wl = (uint4*)wchunk;
    uint4 stage[3];
#pragma unroll
    for (int i = 0; i < 3; ++i) stage[i] = wg[i * 256 + tid];   // chunk kk=0

#pragma unroll
    for (int kk = 0; kk < NKK; ++kk) {
        __syncthreads();                       // previous chunk's readers done
#pragma unroll
        for (int i = 0; i < 3; ++i) wl[i * 256 + tid] = stage[i];
        if (kk + 1 < NKK) {
#pragma unroll
            for (int i = 0; i < 3; ++i)        // prefetch next chunk (overlaps MFMAs)
                stage[i] = wg[(size_t)(kk + 1) * 768 + i * 256 + tid];
        }
        __syncthreads();                       // chunk visible
#pragma unroll
        for (int p = 0; p < 3; ++p)
#pragma unroll
            for (int t = 0; t < 4; ++t) {
                f16x8 bfrag = ((const f16x8*)wchunk)[(p * 4 + t) * 64 + lane];
                acc[p][t] = __builtin_amdgcn_mfma_f32_16x16x32_f16(
                    xf[kk], bfrag, acc[p][t], 0, 0, 0);
            }
    }

    // ---- spill q,k (row-major [t][h]) and v (transposed [h][t]) to LDS ----
    // C/D layout: col h = tile*16 + cl, row t = row0 + quad*4 + r   [m89-verified]
#pragma unroll
    for (int t = 0; t < 4; ++t) {
        int h = t * 16 + cl;
#pragma unroll
        for (int r = 0; r < 4; ++r) {
            int tr = row0 + quad * 4 + r;
            qs [tr * LDP + h] = (f16)acc[0][t][r];
            ksm[tr * LDP + h] = (f16)acc[1][t][r];
        }
        f16x4 vv;
        vv[0]=(f16)acc[2][t][0]; vv[1]=(f16)acc[2][t][1];
        vv[2]=(f16)acc[2][t][2]; vv[3]=(f16)acc[2][t][3];
        *(f16x4*)&vst[h * LDP + row0 + quad * 4] = vv;   // 8B packed store
    }
    __syncthreads();

    // ---- S = q k^T  (wave w owns score rows row0..row0+15, all 64 cols) ----
    floatx4 sa[4];
#pragma unroll
    for (int t = 0; t < 4; ++t) sa[t] = fzero;
#pragma unroll
    for (int kv = 0; kv < 2; ++kv) {
        f16x8 aq = *(const f16x8*)&qs[(row0 + cl) * LDP + kv * 32 + quad * 8];
#pragma unroll
        for (int t = 0; t < 4; ++t) {
            f16x8 bk = *(const f16x8*)&ksm[(t * 16 + cl) * LDP + kv * 32 + quad * 8];
            sa[t] = __builtin_amdgcn_mfma_f32_16x16x32_f16(aq, bk, sa[t], 0, 0, 0);
        }
    }

    // ---- causal softmax: row t = row0+quad*4+r lives in 16 lanes of this quad ----
#pragma unroll
    for (int r = 0; r < 4; ++r) {
        int tr = row0 + quad * 4 + r;
        float v0[4];
        float m = -1e30f;
#pragma unroll
        for (int t = 0; t < 4; ++t) {
            int s = t * 16 + cl;
            float v = sa[t][r] * SCALE;
            v = (s <= tr) ? v : -1e30f;
            v0[t] = v;
            m = fmaxf(m, v);
        }
#pragma unroll
        for (int off = 1; off < 16; off <<= 1) m = fmaxf(m, __shfl_xor(m, off));
        float sum = 0.f;
#pragma unroll
        for (int t = 0; t < 4; ++t) { v0[t] = __expf(v0[t] - m); sum += v0[t]; }
#pragma unroll
        for (int off = 1; off < 16; off <<= 1) sum += __shfl_xor(sum, off);
        float inv = 1.0f / sum;
#pragma unroll
        for (int t = 0; t < 4; ++t)
            ps[tr * LDP + t * 16 + cl] = (f16)(v0[t] * inv);
    }
    __syncthreads();

    // ---- O = P V ----
    floatx4 oa[4];
#pragma unroll
    for (int t = 0; t < 4; ++t) oa[t] = fzero;
#pragma unroll
    for (int kv = 0; kv < 2; ++kv) {
        f16x8 ap = *(const f16x8*)&ps[(row0 + cl) * LDP + kv * 32 + quad * 8];
#pragma unroll
        for (int t = 0; t < 4; ++t) {
            f16x8 bv = *(const f16x8*)&vst[(t * 16 + cl) * LDP + kv * 32 + quad * 8];
            oa[t] = __builtin_amdgcn_mfma_f32_16x16x32_f16(ap, bv, oa[t], 0, 0, 0);
        }
    }

    // ---- store (fp32) ----
    float* op = out + (size_t)b * TT * HH;
#pragma unroll
    for (int t = 0; t < 4; ++t)
#pragma unroll
        for (int r = 0; r < 4; ++r)
            op[(row0 + quad * 4 + r) * HH + t * 16 + cl] = oa[t][r];
}

extern "C" void kernel_launch(void* const* d_in, const int* in_sizes, int n_in,
                              void* d_out, int out_size, void* d_ws, size_t ws_size,
                              hipStream_t stream) {
    const float* x  = (const float*)d_in[0];
    const float* Wq = (const float*)d_in[1];
    const float* Wk = (const float*)d_in[2];
    const float* Wv = (const float*)d_in[3];
    float* out = (float*)d_out;
    f16* wf = (f16*)d_ws;   // needs 3*12*4*64*16 = 147456 bytes

    prep_w<<<36, 256, 0, stream>>>(Wq, Wk, Wv, wf);
    attn_head<<<2048, 256, 0, stream>>>(x, wf, out);
}

// Round 2
// 321.423 us; speedup vs baseline: 1.1934x; 1.1934x over previous
//
#include <hip/hip_runtime.h>
#include <stdint.h>

typedef _Float16 f16;
typedef _Float16 f16x8 __attribute__((ext_vector_type(8)));
typedef _Float16 f16x4 __attribute__((ext_vector_type(4)));
typedef float floatx4 __attribute__((ext_vector_type(4)));
typedef float floatx2 __attribute__((ext_vector_type(2)));

#define TT 64
#define CDIM 384
#define HH 64
#define NKK 12          // CDIM / 32 k-steps
#define LDP 72          // f16 LDS row stride (288 B, 16B-aligned rows)
#define OST 66          // fp32 O-staging row stride (264 B, 8B-aligned rows)
#define SCALE 0.05103103630798288f   // 384^-0.5 (reference scales by C^-0.5)

// Pre-pass: Wq/Wk/Wv -> fp16 in exact MFMA B-fragment order:
// ws layout [kk][p][tile][lane] of f16x8; lane holds W[k=kk*32+quad*8+j][n=tile*16+(lane&15)]
__global__ void prep_w(const float* __restrict__ Wq,
                       const float* __restrict__ Wk,
                       const float* __restrict__ Wv,
                       f16* __restrict__ wf) {
    int t = blockIdx.x * 256 + threadIdx.x;
    if (t >= 3 * NKK * 4 * 64) return;
    int lane = t & 63;
    int tile = (t >> 6) & 3;
    int p    = (t >> 8) % 3;
    int kk   = t / 768;
    const float* W = (p == 0) ? Wq : ((p == 1) ? Wk : Wv);
    int n  = tile * 16 + (lane & 15);
    int k0 = kk * 32 + (lane >> 4) * 8;
    f16x8 frag;
#pragma unroll
    for (int j = 0; j < 8; ++j) frag[j] = (f16)W[(k0 + j) * HH + n];
    ((f16x8*)wf)[t] = frag;
}

__launch_bounds__(256, 4)   // cap VGPR<=128 -> 4 blocks/CU (LDS 36 KB also allows 4)
__global__ void attn_head(const float* __restrict__ x,
                          const f16* __restrict__ wf,
                          float* __restrict__ out) {
    // 36864 B total; ost (16896 B fp32) overlays qs+ksm (18432 B) after they're dead
    __shared__ __align__(16) char smem[4 * TT * LDP * sizeof(f16)];
    f16* qs  = (f16*)smem;
    f16* ksm = qs  + TT * LDP;
    f16* vst = ksm + TT * LDP;   // v transposed: vst[h][t]
    f16* ps  = vst + TT * LDP;
    float* ost = (float*)smem;

    const int b    = blockIdx.x;
    const int tid  = threadIdx.x;
    const int wave = tid >> 6;
    const int lane = tid & 63;
    const int quad = lane >> 4;
    const int cl   = lane & 15;
    const int row0 = wave * 16;

    const floatx4 fzero = {0.f, 0.f, 0.f, 0.f};

    // ---- q,k,v projections: barrier-free K-loop ----
    // x A-fragments loaded per-iteration straight from HBM (no reuse across kk);
    // W B-fragments loaded straight from global (L1/L2-resident, fragment-linear).
    floatx4 acc[3][4];
#pragma unroll
    for (int p = 0; p < 3; ++p)
#pragma unroll
        for (int t = 0; t < 4; ++t) acc[p][t] = fzero;

    const float* xp = x + ((size_t)b * TT + row0 + cl) * CDIM + quad * 8;
    const f16x8* wg = (const f16x8*)wf;

#pragma unroll
    for (int kk = 0; kk < NKK; ++kk) {
        float4 f0 = *(const float4*)(xp + kk * 32);
        float4 f1 = *(const float4*)(xp + kk * 32 + 4);
        f16x8 xf;
        xf[0]=(f16)f0.x; xf[1]=(f16)f0.y; xf[2]=(f16)f0.z; xf[3]=(f16)f0.w;
        xf[4]=(f16)f1.x; xf[5]=(f16)f1.y; xf[6]=(f16)f1.z; xf[7]=(f16)f1.w;
        const f16x8* wk = wg + (size_t)kk * 768 + lane;
#pragma unroll
        for (int p = 0; p < 3; ++p)
#pragma unroll
            for (int t = 0; t < 4; ++t) {
                f16x8 bfrag = wk[(p * 4 + t) * 64];
                acc[p][t] = __builtin_amdgcn_mfma_f32_16x16x32_f16(
                    xf, bfrag, acc[p][t], 0, 0, 0);
            }
    }

    // ---- spill q,k (row-major [t][h]) and v (transposed [h][t]) to LDS ----
    // C/D layout: col h = tile*16 + cl, row t = row0 + quad*4 + r   [m89-verified]
#pragma unroll
    for (int t = 0; t < 4; ++t) {
        int h = t * 16 + cl;
#pragma unroll
        for (int r = 0; r < 4; ++r) {
            int tr = row0 + quad * 4 + r;
            qs [tr * LDP + h] = (f16)acc[0][t][r];
            ksm[tr * LDP + h] = (f16)acc[1][t][r];
        }
        f16x4 vv;
        vv[0]=(f16)acc[2][t][0]; vv[1]=(f16)acc[2][t][1];
        vv[2]=(f16)acc[2][t][2]; vv[3]=(f16)acc[2][t][3];
        *(f16x4*)&vst[h * LDP + row0 + quad * 4] = vv;   // 8B packed store
    }
    __syncthreads();   // barrier A

    // ---- S = q k^T  (wave w owns score rows row0..row0+15, all 64 cols) ----
    floatx4 sa[4];
#pragma unroll
    for (int t = 0; t < 4; ++t) sa[t] = fzero;
#pragma unroll
    for (int kv = 0; kv < 2; ++kv) {
        f16x8 aq = *(const f16x8*)&qs[(row0 + cl) * LDP + kv * 32 + quad * 8];
#pragma unroll
        for (int t = 0; t < 4; ++t) {
            f16x8 bk = *(const f16x8*)&ksm[(t * 16 + cl) * LDP + kv * 32 + quad * 8];
            sa[t] = __builtin_amdgcn_mfma_f32_16x16x32_f16(aq, bk, sa[t], 0, 0, 0);
        }
    }

    // ---- causal softmax: row t = row0+quad*4+r lives in 16 lanes of this quad ----
#pragma unroll
    for (int r = 0; r < 4; ++r) {
        int tr = row0 + quad * 4 + r;
        float v0[4];
        float m = -1e30f;
#pragma unroll
        for (int t = 0; t < 4; ++t) {
            int s = t * 16 + cl;
            float v = sa[t][r] * SCALE;
            v = (s <= tr) ? v : -1e30f;
            v0[t] = v;
            m = fmaxf(m, v);
        }
#pragma unroll
        for (int off = 1; off < 16; off <<= 1) m = fmaxf(m, __shfl_xor(m, off));
        float sum = 0.f;
#pragma unroll
        for (int t = 0; t < 4; ++t) { v0[t] = __expf(v0[t] - m); sum += v0[t]; }
#pragma unroll
        for (int off = 1; off < 16; off <<= 1) sum += __shfl_xor(sum, off);
        float inv = 1.0f / sum;
#pragma unroll
        for (int t = 0; t < 4; ++t)
            ps[tr * LDP + t * 16 + cl] = (f16)(v0[t] * inv);
    }
    __syncthreads();   // barrier B (also retires all qs/ksm readers -> ost overlay safe)

    // ---- O = P V ----
    floatx4 oa[4];
#pragma unroll
    for (int t = 0; t < 4; ++t) oa[t] = fzero;
#pragma unroll
    for (int kv = 0; kv < 2; ++kv) {
        f16x8 ap = *(const f16x8*)&ps[(row0 + cl) * LDP + kv * 32 + quad * 8];
#pragma unroll
        for (int t = 0; t < 4; ++t) {
            f16x8 bv = *(const f16x8*)&vst[(t * 16 + cl) * LDP + kv * 32 + quad * 8];
            oa[t] = __builtin_amdgcn_mfma_f32_16x16x32_f16(ap, bv, oa[t], 0, 0, 0);
        }
    }

    // ---- O through LDS (overlaying dead qs/ksm) for full-line coalesced stores ----
#pragma unroll
    for (int t = 0; t < 4; ++t)
#pragma unroll
        for (int r = 0; r < 4; ++r)
            ost[(row0 + quad * 4 + r) * OST + t * 16 + cl] = oa[t][r];
    __syncthreads();   // barrier C

    float* op = out + (size_t)b * TT * HH;
#pragma unroll
    for (int i = 0; i < 4; ++i) {
        int row = i * 16 + (tid >> 4);
        int c4  = (tid & 15) * 4;
        floatx2 lo = *(const floatx2*)&ost[row * OST + c4];
        floatx2 hi = *(const floatx2*)&ost[row * OST + c4 + 2];
        float4 v; v.x = lo[0]; v.y = lo[1]; v.z = hi[0]; v.w = hi[1];
        *(float4*)&op[row * HH + c4] = v;   // 1 KB contiguous per wave-instruction
    }
}

extern "C" void kernel_launch(void* const* d_in, const int* in_sizes, int n_in,
                              void* d_out, int out_size, void* d_ws, size_t ws_size,
                              hipStream_t stream) {
    const float* x  = (const float*)d_in[0];
    const float* Wq = (const float*)d_in[1];
    const float* Wk = (const float*)d_in[2];
    const float* Wv = (const float*)d_in[3];
    float* out = (float*)d_out;
    f16* wf = (f16*)d_ws;   // needs 3*12*4*64*16 = 147456 bytes

    prep_w<<<36, 256, 0, stream>>>(Wq, Wk, Wv, wf);
    attn_head<<<2048, 256, 0, stream>>>(x, wf, out);
}

// Round 3
// 299.297 us; speedup vs baseline: 1.2816x; 1.0739x over previous
//
#include <hip/hip_runtime.h>
#include <stdint.h>

typedef _Float16 f16;
typedef _Float16 f16x8 __attribute__((ext_vector_type(8)));
typedef _Float16 f16x4 __attribute__((ext_vector_type(4)));
typedef float floatx4 __attribute__((ext_vector_type(4)));
typedef float floatx2 __attribute__((ext_vector_type(2)));

#define TT 64
#define CDIM 384
#define HH 64
#define NKK 12          // CDIM/32 k-steps
#define KH 6            // k-steps per staged half
#define LDP 72          // f16 LDS row stride for q/k/v/p tiles
#define OST 66          // fp32 O-staging row stride
#define SCALE 0.05103103630798288f   // 384^-0.5 (reference scales by C^-0.5)

// Pre-pass: Wq/Wk/Wv -> fp16 in exact MFMA B-fragment order:
// wf layout [kk][p][tile][lane] of f16x8; lane holds W[k=kk*32+quad*8+j][n=tile*16+(lane&15)]
__global__ void prep_w(const float* __restrict__ Wq,
                       const float* __restrict__ Wk,
                       const float* __restrict__ Wv,
                       f16* __restrict__ wf) {
    int t = blockIdx.x * 256 + threadIdx.x;
    if (t >= 3 * NKK * 4 * 64) return;
    int lane = t & 63;
    int tile = (t >> 6) & 3;
    int p    = (t >> 8) % 3;
    int kk   = t / 768;
    const float* W = (p == 0) ? Wq : ((p == 1) ? Wk : Wv);
    int n  = tile * 16 + (lane & 15);
    int k0 = kk * 32 + (lane >> 4) * 8;
    f16x8 frag;
#pragma unroll
    for (int j = 0; j < 8; ++j) frag[j] = (f16)W[(k0 + j) * HH + n];
    ((f16x8*)wf)[t] = frag;
}

static __device__ __forceinline__ f16x8 cvt8(float4 f0, float4 f1) {
    f16x8 h;
    h[0]=(f16)f0.x; h[1]=(f16)f0.y; h[2]=(f16)f0.z; h[3]=(f16)f0.w;
    h[4]=(f16)f1.x; h[5]=(f16)f1.y; h[6]=(f16)f1.z; h[7]=(f16)f1.w;
    return h;
}

__launch_bounds__(256, 4)   // 128 VGPR cap; LDS 36 KB -> 4 blocks/CU
__global__ void attn_head(const float* __restrict__ x,
                          const f16* __restrict__ wf,
                          float* __restrict__ out) {
    // 36864 B. Phase 1: stg (24576 B) holds x A-fragments (one half at a time).
    // Phase 2: qs/ksm/vst/ps (4*9216 B) overlay it. Phase 3: ost overlays qs/ksm.
    __shared__ __align__(16) char smem[4 * TT * LDP * sizeof(f16)];
    f16* stg = (f16*)smem;
    f16* qs  = (f16*)smem;
    f16* ksm = qs  + TT * LDP;
    f16* vst = ksm + TT * LDP;   // v transposed: vst[h][t]
    f16* ps  = vst + TT * LDP;
    float* ost = (float*)smem;

    const int b    = blockIdx.x;
    const int tid  = threadIdx.x;
    const int wave = tid >> 6;
    const int lane = tid & 63;
    const int quad = lane >> 4;
    const int cl   = lane & 15;
    const int row0 = wave * 16;

    // staging role: thread covers row r_st, col-octet qd (8 floats per k-step)
    const int r_st = tid >> 2;
    const int qd   = tid & 3;
    const int l_st = qd * 16 + (r_st & 15);      // lane slot inside A-frag
    const int mt_st = r_st >> 4;                 // m-tile of this row
    const float* xr = x + ((size_t)b * TT + r_st) * CDIM + qd * 8;

    const floatx4 fzero = {0.f, 0.f, 0.f, 0.f};
    floatx4 acc[3][4];
#pragma unroll
    for (int j = 0; j < 3; ++j)
#pragma unroll
        for (int mt = 0; mt < 4; ++mt) acc[j][mt] = fzero;

    const f16x8* wg = (const f16x8*)wf;

    // ---- stage half 0 (kk 0..5) ----
    f16x8 hreg[KH];
#pragma unroll
    for (int i = 0; i < KH; ++i)
        hreg[i] = cvt8(*(const float4*)(xr + i * 32),
                       *(const float4*)(xr + i * 32 + 4));
#pragma unroll
    for (int i = 0; i < KH; ++i)
        *(f16x8*)&stg[((i * 4 + mt_st) * 64 + l_st) * 8] = hreg[i];
    __syncthreads();                                    // B1: half-0 visible

    // prefetch half 1 x into registers (overlaps the 72 MFMAs below)
#pragma unroll
    for (int i = 0; i < KH; ++i)
        hreg[i] = cvt8(*(const float4*)(xr + (KH + i) * 32),
                       *(const float4*)(xr + (KH + i) * 32 + 4));

    // ---- compute halves: wave owns tiles T=3*wave+j over all 4 m-tiles ----
#pragma unroll
    for (int i = 0; i < KH; ++i) {
        f16x8 af[4];
#pragma unroll
        for (int mt = 0; mt < 4; ++mt)
            af[mt] = *(const f16x8*)&stg[((i * 4 + mt) * 64 + lane) * 8];
#pragma unroll
        for (int j = 0; j < 3; ++j) {
            f16x8 bf = wg[(size_t)i * 768 + (wave * 3 + j) * 64 + lane];
#pragma unroll
            for (int mt = 0; mt < 4; ++mt)
                acc[j][mt] = __builtin_amdgcn_mfma_f32_16x16x32_f16(
                    af[mt], bf, acc[j][mt], 0, 0, 0);
        }
    }
    __syncthreads();                                    // B2: half-0 readers done
#pragma unroll
    for (int i = 0; i < KH; ++i)
        *(f16x8*)&stg[((i * 4 + mt_st) * 64 + l_st) * 8] = hreg[i];
    __syncthreads();                                    // B3: half-1 visible
#pragma unroll
    for (int i = 0; i < KH; ++i) {
        f16x8 af[4];
#pragma unroll
        for (int mt = 0; mt < 4; ++mt)
            af[mt] = *(const f16x8*)&stg[((i * 4 + mt) * 64 + lane) * 8];
#pragma unroll
        for (int j = 0; j < 3; ++j) {
            f16x8 bf = wg[(size_t)(KH + i) * 768 + (wave * 3 + j) * 64 + lane];
#pragma unroll
            for (int mt = 0; mt < 4; ++mt)
                acc[j][mt] = __builtin_amdgcn_mfma_f32_16x16x32_f16(
                    af[mt], bf, acc[j][mt], 0, 0, 0);
        }
    }
    __syncthreads();                                    // B4: stg readers done

    // ---- spill q,k (row-major [t][h]) and v (transposed [h][t]) to LDS ----
    // C/D layout: col = tile*16 + cl, row = mt*16 + quad*4 + r   [m89-verified]
#pragma unroll
    for (int j = 0; j < 3; ++j) {
        int T  = wave * 3 + j;
        int p  = T >> 2;
        int h  = (T & 3) * 16 + cl;
        if (p == 2) {
#pragma unroll
            for (int mt = 0; mt < 4; ++mt) {
                f16x4 vv;
                vv[0]=(f16)acc[j][mt][0]; vv[1]=(f16)acc[j][mt][1];
                vv[2]=(f16)acc[j][mt][2]; vv[3]=(f16)acc[j][mt][3];
                *(f16x4*)&vst[h * LDP + mt * 16 + quad * 4] = vv;
            }
        } else {
            f16* dst = (p == 0) ? qs : ksm;
#pragma unroll
            for (int mt = 0; mt < 4; ++mt)
#pragma unroll
                for (int r = 0; r < 4; ++r)
                    dst[(mt * 16 + quad * 4 + r) * LDP + h] = (f16)acc[j][mt][r];
        }
    }
    __syncthreads();                                    // barrier A

    // ---- S = q k^T  (wave w owns score rows row0..row0+15, all 64 cols) ----
    floatx4 sa[4];
#pragma unroll
    for (int t = 0; t < 4; ++t) sa[t] = fzero;
#pragma unroll
    for (int kv = 0; kv < 2; ++kv) {
        f16x8 aq = *(const f16x8*)&qs[(row0 + cl) * LDP + kv * 32 + quad * 8];
#pragma unroll
        for (int t = 0; t < 4; ++t) {
            f16x8 bk = *(const f16x8*)&ksm[(t * 16 + cl) * LDP + kv * 32 + quad * 8];
            sa[t] = __builtin_amdgcn_mfma_f32_16x16x32_f16(aq, bk, sa[t], 0, 0, 0);
        }
    }

    // ---- causal softmax: row t = row0+quad*4+r lives in 16 lanes of this quad ----
#pragma unroll
    for (int r = 0; r < 4; ++r) {
        int tr = row0 + quad * 4 + r;
        float v0[4];
        float m = -1e30f;
#pragma unroll
        for (int t = 0; t < 4; ++t) {
            int s = t * 16 + cl;
            float v = sa[t][r] * SCALE;
            v = (s <= tr) ? v : -1e30f;
            v0[t] = v;
            m = fmaxf(m, v);
        }
#pragma unroll
        for (int off = 1; off < 16; off <<= 1) m = fmaxf(m, __shfl_xor(m, off));
        float sum = 0.f;
#pragma unroll
        for (int t = 0; t < 4; ++t) { v0[t] = __expf(v0[t] - m); sum += v0[t]; }
#pragma unroll
        for (int off = 1; off < 16; off <<= 1) sum += __shfl_xor(sum, off);
        float inv = 1.0f / sum;
#pragma unroll
        for (int t = 0; t < 4; ++t)
            ps[tr * LDP + t * 16 + cl] = (f16)(v0[t] * inv);
    }
    __syncthreads();                                    // barrier B

    // ---- O = P V ----
    floatx4 oa[4];
#pragma unroll
    for (int t = 0; t < 4; ++t) oa[t] = fzero;
#pragma unroll
    for (int kv = 0; kv < 2; ++kv) {
        f16x8 ap = *(const f16x8*)&ps[(row0 + cl) * LDP + kv * 32 + quad * 8];
#pragma unroll
        for (int t = 0; t < 4; ++t) {
            f16x8 bv = *(const f16x8*)&vst[(t * 16 + cl) * LDP + kv * 32 + quad * 8];
            oa[t] = __builtin_amdgcn_mfma_f32_16x16x32_f16(ap, bv, oa[t], 0, 0, 0);
        }
    }

    // ---- O through LDS (overlaying dead qs/ksm) for full-line coalesced stores ----
#pragma unroll
    for (int t = 0; t < 4; ++t)
#pragma unroll
        for (int r = 0; r < 4; ++r)
            ost[(row0 + quad * 4 + r) * OST + t * 16 + cl] = oa[t][r];
    __syncthreads();                                    // barrier C

    float* op = out + (size_t)b * TT * HH;
#pragma unroll
    for (int i = 0; i < 4; ++i) {
        int row = i * 16 + (tid >> 4);
        int c4  = (tid & 15) * 4;
        floatx2 lo = *(const floatx2*)&ost[row * OST + c4];
        floatx2 hi = *(const floatx2*)&ost[row * OST + c4 + 2];
        float4 v; v.x = lo[0]; v.y = lo[1]; v.z = hi[0]; v.w = hi[1];
        *(float4*)&op[row * HH + c4] = v;   // 1 KB contiguous per wave-instruction
    }
}

extern "C" void kernel_launch(void* const* d_in, const int* in_sizes, int n_in,
                              void* d_out, int out_size, void* d_ws, size_t ws_size,
                              hipStream_t stream) {
    const float* x  = (const float*)d_in[0];
    const float* Wq = (const float*)d_in[1];
    const float* Wk = (const float*)d_in[2];
    const float* Wv = (const float*)d_in[3];
    float* out = (float*)d_out;
    f16* wf = (f16*)d_ws;   // needs 3*12*4*64*16 = 147456 bytes

    prep_w<<<36, 256, 0, stream>>>(Wq, Wk, Wv, wf);
    attn_head<<<2048, 256, 0, stream>>>(x, wf, out);
}